// Round 10
// baseline (773.068 us; speedup 1.0000x reference)
//
#include <hip/hip_runtime.h>
#include <hip/hip_cooperative_groups.h>
#include <math.h>

namespace cg = cooperative_groups;

// MoE FFN, routed (top-2 pair-grouped), round 10: cooperative persistent
// kernel with occupancy-sized grid + deterministic multi-launch fallback.
// Phases (shared __device__ bodies):
//   prep: router(f64)+xb, pack w1/w2 swizzled images, ltw transpose, init
//   build (1 block): hist -> tile meta      scatter: tokens -> slots
//   G1: 64x128 BK=128 images                G2: 64x128 BK=128, XCD-pinned
//   G3: 128x128 BK=64 strided + bias, XCD-owned M groups
// Image swizzle: elem(r,k) at r*128 + (((k>>3)^(r&15))<<3 | (k&7)).

using short8  = __attribute__((ext_vector_type(8))) short;
using floatx4 = __attribute__((ext_vector_type(4))) float;
typedef unsigned short bf16_t;

#define TOK   8192
#define HDIM  1024
#define RDIM  256
#define FDIM  4096
#define NEXP  8
#define MAXTILES 96
#define IMG   16384
#define NPREP 3776
#define NG1   (8 * MAXTILES)
#define NG2   (64 * MAXTILES)
#define NG3   512

__device__ __forceinline__ bf16_t f2bf(float f) {
  union { float f; unsigned u; } a; a.f = f;
  unsigned u = a.u;
  return (bf16_t)((u + 0x7FFFu + ((u >> 16) & 1u)) >> 16);  // RNE
}

__device__ __forceinline__ float gelu_erf(float v) {
  return 0.5f * v * (1.0f + erff(v * 0.70710678118654752f));
}

__device__ __forceinline__ void gload16(const void* g, void* l) {
  __builtin_amdgcn_global_load_lds(
      (const __attribute__((address_space(1))) void*)g,
      (__attribute__((address_space(3))) void*)l, 16, 0, 0);
}

__device__ __forceinline__ int swz_off(int r, int kl) {
  return r * 128 + ((((kl >> 3) ^ (r & 15)) << 3) | (kl & 7));
}

// ---------------------------------------------------------------- phases

__device__ void phase_prep(int vb, char* smem,
                           const float* __restrict__ x, const float* __restrict__ rw,
                           const float* __restrict__ rb, const float* __restrict__ w1,
                           const float* __restrict__ w2, const float* __restrict__ l2w,
                           int* __restrict__ gid_tok, float2* __restrict__ tokscale,
                           bf16_t* __restrict__ xb, bf16_t* __restrict__ w1p,
                           bf16_t* __restrict__ w2p, bf16_t* __restrict__ ltw,
                           int* __restrict__ tokslot, float2* __restrict__ slotsc,
                           int* __restrict__ ctrl) {
  const int t = threadIdx.x;
  const int lane = t & 63;
  if (vb < 2048) {
    // router: f64 logits (selection-safe vs np ref) + xb emit
    const int token = vb * 4 + (t >> 6);
    const float* xr = x + (size_t)token * HDIM;
    bf16_t* xbr = xb + (size_t)token * HDIM;
    double acc[NEXP];
#pragma unroll
    for (int e = 0; e < NEXP; e++) acc[e] = 0.0;
    for (int h = lane; h < HDIM; h += 64) {
      const float xf = xr[h];
      xbr[h] = f2bf(xf);
      const double xv = (double)xf;
      const float* wr = rw + (size_t)h * NEXP;
#pragma unroll
      for (int e = 0; e < NEXP; e++) acc[e] += xv * (double)wr[e];
    }
#pragma unroll
    for (int off = 32; off > 0; off >>= 1) {
#pragma unroll
      for (int e = 0; e < NEXP; e++) acc[e] += __shfl_xor(acc[e], off, 64);
    }
    double lg[NEXP];
#pragma unroll
    for (int e = 0; e < NEXP; e++) lg[e] = acc[e] + (double)rb[e];
    double mx = lg[0];
#pragma unroll
    for (int e = 1; e < NEXP; e++) mx = fmax(mx, lg[e]);
    double p[NEXP]; double den = 0.0;
#pragma unroll
    for (int e = 0; e < NEXP; e++) { p[e] = exp(lg[e] - mx); den += p[e]; }
    int i1 = 0;
#pragma unroll
    for (int e = 1; e < NEXP; e++) if (lg[e] > lg[i1]) i1 = e;
    int i2 = (i1 == 0) ? 1 : 0;
#pragma unroll
    for (int e = 0; e < NEXP; e++)
      if (e != i1 && e != i2 && lg[e] > lg[i2]) i2 = e;
    if (lane == 0) {
      const int elo = min(i1, i2), ehi = max(i1, i2);
      gid_tok[token] = elo * 8 + ehi;
      tokscale[token] = make_float2((float)(p[elo] / den), (float)(p[ehi] / den));
    }
  } else if (vb < 2688) {
    // pack w1 / w2 -> swizzled 128x128 images
    const float* src; bf16_t* dst; size_t ks;
    if (vb < 2176) {
      const int img = vb - 2048;
      const int e = img >> 4, nc = (img >> 3) & 1, kb = img & 7;
      src = w1 + (size_t)e * 1024 * 256 + (size_t)kb * 128 * 256 + nc * 128;
      ks = 256; dst = w1p + (size_t)img * IMG;
    } else {
      const int img = vb - 2176;
      const int n = img >> 4, e = (img >> 1) & 7, kb = img & 1;
      src = w2 + (size_t)e * 256 * 4096 + (size_t)kb * 128 * 4096 + n * 128;
      ks = 4096; dst = w2p + (size_t)img * IMG;
    }
    bf16_t* lim = (bf16_t*)smem;
    const int rr = t & 127, half = t >> 7;
    for (int kl = half; kl < 128; kl += 2)
      lim[swz_off(rr, kl)] = f2bf(src[(size_t)kl * ks + rr]);
    __syncthreads();
    const int4* s4 = (const int4*)lim;
    int4* d4 = (int4*)dst;
#pragma unroll
    for (int i = 0; i < 8; i++) d4[t + i * 256] = s4[t + i * 256];
  } else if (vb < 3712) {
    // lin2_w [F][H] -> ltw[h][f] row-major bf16, 64x64 tiles
    float* tile = (float*)smem;  // [64][65]
    const int bid = vb - 2688;
    const int c0 = (bid & 15) * 64;
    const int r0 = (bid >> 4) * 64;
    const int tx = t & 63, ty = t >> 6;
#pragma unroll
    for (int i = 0; i < 64; i += 4)
      tile[(ty + i) * 65 + tx] = l2w[(size_t)(r0 + ty + i) * HDIM + (c0 + tx)];
    __syncthreads();
#pragma unroll
    for (int i = 0; i < 64; i += 4)
      ltw[(size_t)(c0 + ty + i) * FDIM + (r0 + tx)] = f2bf(tile[tx * 65 + ty + i]);
  } else {
    const int i = (vb - 3712) * 256 + t;
    tokslot[i] = -1;
    slotsc[i] = make_float2(0.f, 0.f);
    if (vb == 3712 && t < 64) ctrl[64 + t] = 0;  // fill counters
  }
}

__device__ void phase_build(char* smem, const int* __restrict__ gid_tok,
                            int* __restrict__ ctrl) {
  int* hist = (int*)smem;
  int* ntl  = hist + 64;
  const int t = threadIdx.x;
  if (t < 64) hist[t] = 0;
  __syncthreads();
  for (int i = t; i < TOK; i += 256) atomicAdd(&hist[gid_tok[i]], 1);
  __syncthreads();
  if (t < 64) ntl[t] = (hist[t] + 127) >> 7;
  __syncthreads();
  if (t < 64) {
    int slot0 = 0, tile0 = 0;
    for (int g = 0; g < t; g++) { slot0 += ntl[g] << 7; tile0 += ntl[g]; }
    ctrl[128 + t] = slot0;
    const int nt = ntl[t], c = hist[t];
    for (int i = 0; i < nt; i++) {
      ctrl[256 + (tile0 + i) * 3 + 0] = t;
      ctrl[256 + (tile0 + i) * 3 + 1] = slot0 + i * 128;
      ctrl[256 + (tile0 + i) * 3 + 2] = min(128, c - i * 128);
    }
    if (t == 63) ctrl[192] = tile0 + nt;
  }
}

__device__ void phase_scatter(int i0, int stride, const int* __restrict__ gid_tok,
                              const float2* __restrict__ tokscale,
                              int* __restrict__ ctrl, int* __restrict__ tokslot,
                              float2* __restrict__ slotsc) {
  for (int i = i0; i < TOK; i += stride) {
    const int g = gid_tok[i];
    const int pos = atomicAdd(&ctrl[64 + g], 1);
    const int slot = ctrl[128 + g] + pos;
    tokslot[slot] = i;
    slotsc[slot] = tokscale[i];
  }
}

// G1: 64x128 BK=128. vb: n = vb&3, mh = (vb>>2)&1, tile = vb>>3.
__device__ void phase_g1(int vb, char* smem,
                         const bf16_t* __restrict__ xb, const bf16_t* __restrict__ w1p,
                         bf16_t* __restrict__ Tp, const int* __restrict__ ctrl,
                         const int* __restrict__ tokslot,
                         const float2* __restrict__ slotsc) {
  const int n = vb & 3, mh = (vb >> 2) & 1, tile = vb >> 3;
  if (tile >= ctrl[192]) return;
  const int nrows = ctrl[256 + tile * 3 + 2];
  if (mh && nrows <= 64) return;
  bf16_t* As = (bf16_t*)smem;             // 16 KB
  bf16_t* Bs = (bf16_t*)(smem + 16384);   // 32 KB
  const int gid   = ctrl[256 + tile * 3];
  const int slot0 = ctrl[256 + tile * 3 + 1];
  const int e = (n < 2) ? (gid >> 3) : (gid & 7);
  const int nc = n & 1;
  const int t = threadIdx.x, lane = t & 63, w = t >> 6;
  const int l16 = lane & 15, quad = lane >> 4;
  const int wm = (w & 1) * 32, wn = (w >> 1) * 64;

  floatx4 acc[2][4];
  const floatx4 zero = {0.f, 0.f, 0.f, 0.f};
#pragma unroll
  for (int i = 0; i < 2; i++)
#pragma unroll
    for (int j = 0; j < 4; j++) acc[i][j] = zero;

  int toks[4], rowAs[4];
#pragma unroll
  for (int i = 0; i < 4; i++) {
    rowAs[i] = w * 16 + i * 4 + (lane >> 4);
    int tk = tokslot[slot0 + mh * 64 + rowAs[i]];
    toks[i] = (tk < 0) ? 0 : tk;
  }
  const bf16_t* bimg = w1p + (size_t)(e * 16 + nc * 8) * IMG;
  bf16_t* lA = As + w * 2048;
  bf16_t* lB = Bs + w * 4096;

  for (int kb = 0; kb < 8; kb++) {
    __syncthreads();
#pragma unroll
    for (int i = 0; i < 4; i++) {
      const int gq = (lane & 15) ^ (rowAs[i] & 15);
      gload16(xb + (size_t)toks[i] * HDIM + kb * 128 + gq * 8, lA + i * 512);
    }
#pragma unroll
    for (int i = 0; i < 8; i++)
      gload16(bimg + (size_t)kb * IMG + w * 4096 + i * 512 + lane * 8, lB + i * 512);
    __syncthreads();
#pragma unroll
    for (int s = 0; s < 4; s++) {
      const int pg = ((s * 4 + quad) ^ l16) << 3;
      short8 af[2], bfr[4];
#pragma unroll
      for (int i = 0; i < 2; i++)
        af[i] = *(const short8*)&As[(wm + i * 16 + l16) * 128 + pg];
#pragma unroll
      for (int i = 0; i < 4; i++)
        bfr[i] = *(const short8*)&Bs[(wn + i * 16 + l16) * 128 + pg];
#pragma unroll
      for (int mi = 0; mi < 2; mi++)
#pragma unroll
        for (int ni = 0; ni < 4; ni++)
          acc[mi][ni] = __builtin_amdgcn_mfma_f32_16x16x32_bf16(
              af[mi], bfr[ni], acc[mi][ni], 0, 0, 0);
    }
  }

  __syncthreads();
#pragma unroll
  for (int mi = 0; mi < 2; mi++) {
#pragma unroll
    for (int r = 0; r < 4; r++) {
      const int rloc = wm + mi * 16 + quad * 4 + r;
      const float2 sc = slotsc[slot0 + mh * 64 + rloc];
      const float s = (n < 2) ? sc.x : sc.y;
#pragma unroll
      for (int ni = 0; ni < 4; ni++) {
        const int c = wn + ni * 16 + l16;
        As[swz_off(rloc, c)] = f2bf(acc[mi][ni][r] * s);
      }
    }
  }
  __syncthreads();
  bf16_t* img = Tp + (size_t)(tile * 4 + n) * IMG + mh * 64 * 128;
  const int4* s4 = (const int4*)As;
  int4* d4 = (int4*)img;
#pragma unroll
  for (int j = 0; j < 4; j++) d4[t + j * 256] = s4[t + j * 256];
}

// G2: 64x128 BK=128, XCD pinned by n-group (strides are 0 mod 8).
// vb: n = (vb&7)*4 + ((vb>>3)&3), mh = (vb>>5)&1, tile = vb>>6.
__device__ void phase_g2(int vb, char* smem,
                         const bf16_t* __restrict__ Tp, const bf16_t* __restrict__ w2p,
                         bf16_t* __restrict__ Hb, const int* __restrict__ ctrl,
                         const int* __restrict__ tokslot) {
  const int n = (vb & 7) * 4 + ((vb >> 3) & 3);
  const int mh = (vb >> 5) & 1, tile = vb >> 6;
  if (tile >= ctrl[192]) return;
  const int nrows = ctrl[256 + tile * 3 + 2];
  if (mh && nrows <= 64) return;
  bf16_t* As = (bf16_t*)smem;
  bf16_t* Bs = (bf16_t*)(smem + 16384);
  const int gid   = ctrl[256 + tile * 3];
  const int slot0 = ctrl[256 + tile * 3 + 1];
  const int elo = gid >> 3, ehi = gid & 7;
  const int t = threadIdx.x, lane = t & 63, w = t >> 6;
  const int l16 = lane & 15, quad = lane >> 4;
  const int wm = (w & 1) * 32, wn = (w >> 1) * 64;

  floatx4 acc[2][4];
  const floatx4 zero = {0.f, 0.f, 0.f, 0.f};
#pragma unroll
  for (int i = 0; i < 2; i++)
#pragma unroll
    for (int j = 0; j < 4; j++) acc[i][j] = zero;

  const bf16_t* aimg = Tp + (size_t)tile * 4 * IMG + mh * 64 * 128;
  bf16_t* lA = As + w * 2048;
  bf16_t* lB = Bs + w * 4096;

#pragma unroll
  for (int tt = 0; tt < 4; tt++) {
    const int e = (tt < 2) ? elo : ehi;
    const bf16_t* bimg = w2p + (size_t)(n * 16 + e * 2 + (tt & 1)) * IMG;
    __syncthreads();
#pragma unroll
    for (int i = 0; i < 4; i++)
      gload16(aimg + (size_t)tt * IMG + w * 2048 + i * 512 + lane * 8, lA + i * 512);
#pragma unroll
    for (int i = 0; i < 8; i++)
      gload16(bimg + w * 4096 + i * 512 + lane * 8, lB + i * 512);
    __syncthreads();
#pragma unroll
    for (int s = 0; s < 4; s++) {
      const int pg = ((s * 4 + quad) ^ l16) << 3;
      short8 af[2], bfr[4];
#pragma unroll
      for (int i = 0; i < 2; i++)
        af[i] = *(const short8*)&As[(wm + i * 16 + l16) * 128 + pg];
#pragma unroll
      for (int i = 0; i < 4; i++)
        bfr[i] = *(const short8*)&Bs[(wn + i * 16 + l16) * 128 + pg];
#pragma unroll
      for (int mi = 0; mi < 2; mi++)
#pragma unroll
        for (int ni = 0; ni < 4; ni++)
          acc[mi][ni] = __builtin_amdgcn_mfma_f32_16x16x32_bf16(
              af[mi], bfr[ni], acc[mi][ni], 0, 0, 0);
    }
  }

  // epilogue: gelu -> Bs row-major [64][128] -> coalesced token-row bursts
  __syncthreads();
#pragma unroll
  for (int mi = 0; mi < 2; mi++) {
#pragma unroll
    for (int r = 0; r < 4; r++) {
      const int rloc = wm + mi * 16 + quad * 4 + r;
#pragma unroll
      for (int ni = 0; ni < 4; ni++) {
        const int c = wn + ni * 16 + l16;
        Bs[rloc * 128 + c] = f2bf(gelu_erf(acc[mi][ni][r]));
      }
    }
  }
  __syncthreads();
  const int4* s4 = (const int4*)Bs;
#pragma unroll
  for (int j = 0; j < 4; j++) {
    const int chunk = t + j * 256;
    const int row = chunk >> 4, off = chunk & 15;
    const int tok = tokslot[slot0 + mh * 64 + row];
    if (tok >= 0)
      *(int4*)(Hb + (size_t)tok * FDIM + n * 128 + off * 8) = s4[chunk];
  }
}

// G3: 128x128 BK=64 strided, XCD-owned M groups, bias fused.
// vb: m0 = ((vb&7)*8 + ((vb>>3)&7))*128, n0 = (vb>>6)*128.
__device__ void phase_g3(int vb, char* smem,
                         const bf16_t* __restrict__ Hb, const bf16_t* __restrict__ ltw,
                         float* __restrict__ out, const float* __restrict__ bias) {
  bf16_t* As = (bf16_t*)smem;             // 16 KB (128x64)
  bf16_t* Bs = (bf16_t*)(smem + 16384);   // 16 KB (128x64)
  const int m0 = ((vb & 7) * 8 + ((vb >> 3) & 7)) * 128;
  const int n0 = (vb >> 6) * 128;
  const int t = threadIdx.x, lane = t & 63, w = t >> 6;
  const int l16 = lane & 15, quad = lane >> 4;
  const int wm = (w >> 1) * 64, wn = (w & 1) * 64;
  const int rl = lane >> 3, gq = lane & 7;
  const int gf = (gq ^ rl) * 8;

  floatx4 acc[4][4];
  const floatx4 zero = {0.f, 0.f, 0.f, 0.f};
#pragma unroll
  for (int i = 0; i < 4; i++)
#pragma unroll
    for (int j = 0; j < 4; j++) acc[i][j] = zero;

  const bf16_t* ga[4];
  const bf16_t* gb[4];
#pragma unroll
  for (int c = 0; c < 4; c++) {
    ga[c] = Hb  + (size_t)(m0 + w * 32 + c * 8 + rl) * FDIM + gf;
    gb[c] = ltw + (size_t)(n0 + w * 32 + c * 8 + rl) * FDIM + gf;
  }
  bf16_t* lA = As + w * 2048;
  bf16_t* lB = Bs + w * 2048;

  for (int k0 = 0; k0 < FDIM; k0 += 64) {
    __syncthreads();
#pragma unroll
    for (int c = 0; c < 4; c++) { gload16(ga[c], lA + c * 512); ga[c] += 64; }
#pragma unroll
    for (int c = 0; c < 4; c++) { gload16(gb[c], lB + c * 512); gb[c] += 64; }
    __syncthreads();
#pragma unroll
    for (int s = 0; s < 2; s++) {
      const int pg = ((s * 4 + quad) ^ (l16 & 7)) * 8;
      short8 af[4], bfr[4];
#pragma unroll
      for (int i = 0; i < 4; i++)
        af[i] = *(const short8*)&As[(wm + i * 16 + l16) * 64 + pg];
#pragma unroll
      for (int i = 0; i < 4; i++)
        bfr[i] = *(const short8*)&Bs[(wn + i * 16 + l16) * 64 + pg];
#pragma unroll
      for (int mi = 0; mi < 4; mi++)
#pragma unroll
        for (int ni = 0; ni < 4; ni++)
          acc[mi][ni] = __builtin_amdgcn_mfma_f32_16x16x32_bf16(
              af[mi], bfr[ni], acc[mi][ni], 0, 0, 0);
    }
  }

#pragma unroll
  for (int mi = 0; mi < 4; mi++) {
#pragma unroll
    for (int ni = 0; ni < 4; ni++) {
      const int row = m0 + wm + mi * 16 + quad * 4;
      const int col = n0 + wn + ni * 16 + l16;
#pragma unroll
      for (int r = 0; r < 4; r++)
        out[(size_t)(row + r) * HDIM + col] = acc[mi][ni][r] + bias[col];
    }
  }
}

// ---------------------------------------------------------------- kernels

__global__ __launch_bounds__(256, 2)
void mega(const float* x, const float* rw, const float* rb, const float* w1,
          const float* w2, const float* l2w, const float* l2b,
          int* gid_tok, float2* tokscale, bf16_t* xb, bf16_t* w1p,
          bf16_t* w2p, bf16_t* ltw, int* tokslot, float2* slotsc,
          int* ctrl, bf16_t* Tp, bf16_t* Hb, float* out) {
  cg::grid_group gg = cg::this_grid();
  __shared__ __align__(16) char smem[49152];
  const int b = blockIdx.x, G = gridDim.x;
  for (int vb = b; vb < NPREP; vb += G) {
    __syncthreads();
    phase_prep(vb, smem, x, rw, rb, w1, w2, l2w, gid_tok, tokscale,
               xb, w1p, w2p, ltw, tokslot, slotsc, ctrl);
  }
  gg.sync();
  if (b == 0) phase_build(smem, gid_tok, ctrl);
  gg.sync();
  phase_scatter(b * 256 + threadIdx.x, G * 256, gid_tok, tokscale, ctrl,
                tokslot, slotsc);
  gg.sync();
  for (int vb = b; vb < NG1; vb += G)
    phase_g1(vb, smem, xb, w1p, Tp, ctrl, tokslot, slotsc);
  gg.sync();
  for (int vb = b; vb < NG2; vb += G)
    phase_g2(vb, smem, Tp, w2p, Hb, ctrl, tokslot);
  gg.sync();
  for (int vb = b; vb < NG3; vb += G)
    phase_g3(vb, smem, Hb, ltw, out, l2b);
}

__global__ __launch_bounds__(256)
void k_prep(const float* x, const float* rw, const float* rb, const float* w1,
            const float* w2, const float* l2w, int* gid_tok, float2* tokscale,
            bf16_t* xb, bf16_t* w1p, bf16_t* w2p, bf16_t* ltw,
            int* tokslot, float2* slotsc, int* ctrl) {
  __shared__ __align__(16) char smem[32768];
  phase_prep(blockIdx.x, smem, x, rw, rb, w1, w2, l2w, gid_tok, tokscale,
             xb, w1p, w2p, ltw, tokslot, slotsc, ctrl);
}

__global__ void k_build(const int* gid_tok, int* ctrl) {
  __shared__ __align__(16) char smem[512];
  phase_build(smem, gid_tok, ctrl);
}

__global__ void k_scatter(const int* gid_tok, const float2* tokscale, int* ctrl,
                          int* tokslot, float2* slotsc) {
  phase_scatter(blockIdx.x * 256 + threadIdx.x, gridDim.x * 256, gid_tok,
                tokscale, ctrl, tokslot, slotsc);
}

__global__ __launch_bounds__(256)
void k_g1(const bf16_t* xb, const bf16_t* w1p, bf16_t* Tp, const int* ctrl,
          const int* tokslot, const float2* slotsc) {
  __shared__ __align__(16) char smem[49152];
  phase_g1(blockIdx.x, smem, xb, w1p, Tp, ctrl, tokslot, slotsc);
}

__global__ __launch_bounds__(256)
void k_g2(const bf16_t* Tp, const bf16_t* w2p, bf16_t* Hb, const int* ctrl,
          const int* tokslot) {
  __shared__ __align__(16) char smem[49152];
  phase_g2(blockIdx.x, smem, Tp, w2p, Hb, ctrl, tokslot);
}

__global__ __launch_bounds__(256)
void k_g3(const bf16_t* Hb, const bf16_t* ltw, float* out, const float* bias) {
  __shared__ __align__(16) char smem[32768];
  phase_g3(blockIdx.x, smem, Hb, ltw, out, bias);
}

// ---------------------------------------------------------------- launch

extern "C" void kernel_launch(void* const* d_in, const int* in_sizes, int n_in,
                              void* d_out, int out_size, void* d_ws, size_t ws_size,
                              hipStream_t stream) {
  const float* x   = (const float*)d_in[0];
  const float* rw  = (const float*)d_in[1];
  const float* rb  = (const float*)d_in[2];
  const float* w1  = (const float*)d_in[3];
  const float* w2  = (const float*)d_in[4];
  const float* l2w = (const float*)d_in[5];
  const float* l2b = (const float*)d_in[6];

  char* ws = (char*)d_ws;
  int*    ctrl     = (int*)   (ws + 0);
  int*    gid_tok  = (int*)   (ws + 4096);
  float2* tokscale = (float2*)(ws + 36864);
  int*    tokslot  = (int*)   (ws + 102400);
  float2* slotsc   = (float2*)(ws + 167936);
  bf16_t* xb  = (bf16_t*)(ws + 1048576);        // 16.78 MB
  bf16_t* w1p = (bf16_t*)(ws + 17825792);       //  4.19 MB (128 images)
  bf16_t* w2p = (bf16_t*)(ws + 22020096);       // 16.78 MB (512 images)
  bf16_t* ltw = (bf16_t*)(ws + 38797312);       //  8.39 MB (row-major [h][f])
  bf16_t* Tp  = (bf16_t*)(ws + 47185920);       // 12.58 MB (96*4 images)
  bf16_t* Hb  = (bf16_t*)(ws + 59768832);       // 67.11 MB -> end 126,877,696
  float*  outp = (float*)d_out;

  // try cooperative persistent kernel (occupancy-sized grid)
  int nb = 0;
  hipError_t err = hipOccupancyMaxActiveBlocksPerMultiprocessor(
      &nb, (const void*)mega, 256, 0);
  if (err == hipSuccess && nb > 0) {
    int grid = nb * 256;
    if (grid > 512) grid = 512;
    void* args[] = {
      (void*)&x, (void*)&rw, (void*)&rb, (void*)&w1, (void*)&w2, (void*)&l2w,
      (void*)&l2b, (void*)&gid_tok, (void*)&tokscale, (void*)&xb, (void*)&w1p,
      (void*)&w2p, (void*)&ltw, (void*)&tokslot, (void*)&slotsc, (void*)&ctrl,
      (void*)&Tp, (void*)&Hb, (void*)&outp,
    };
    err = hipLaunchCooperativeKernel((const void*)mega, dim3(grid), dim3(256),
                                     args, 0, stream);
  } else if (err == hipSuccess) {
    err = hipErrorUnknown;
  }

  if (err != hipSuccess) {
    // deterministic fallback: identical phases as ordinary launches
    k_prep<<<NPREP, 256, 0, stream>>>(x, rw, rb, w1, w2, l2w, gid_tok,
                                      tokscale, xb, w1p, w2p, ltw,
                                      tokslot, slotsc, ctrl);
    k_build<<<1, 256, 0, stream>>>(gid_tok, ctrl);
    k_scatter<<<TOK / 256 / 8, 256, 0, stream>>>(gid_tok, tokscale, ctrl,
                                                 tokslot, slotsc);
    k_g1<<<NG1, 256, 0, stream>>>(xb, w1p, Tp, ctrl, tokslot, slotsc);
    k_g2<<<NG2, 256, 0, stream>>>(Tp, w2p, Hb, ctrl, tokslot);
    k_g3<<<NG3, 256, 0, stream>>>(Hb, ltw, outp, l2b);
  }
}